// Round 5
// baseline (815.673 us; speedup 1.0000x reference)
//
#include <hip/hip_runtime.h>
#include <hip/hip_bf16.h>
#include <stdint.h>

#define D_MODEL 1024
#define D_FF    4096
#define N_EXP   8
#define TOPK    2
#define NTOK    8192
#define NASSIGN (NTOK*TOPK)

#define BM 128
#define BN 128
#define BK 64
#define THREADS 256
#define SPLITK 4          // gemm2 K-split: 4096 -> 4 x 1024

typedef __bf16 bf16_t;
typedef __attribute__((ext_vector_type(8))) bf16_t bf16x8;
typedef __attribute__((ext_vector_type(4))) float f32x4;

__device__ __forceinline__ unsigned short f2bf(float f) {
    bf16_t b = (bf16_t)f;
    return __builtin_bit_cast(unsigned short, b);
}

__device__ __forceinline__ void gload_lds16(const void* g, void* l) {
    __builtin_amdgcn_global_load_lds(
        (const __attribute__((address_space(1))) void*)g,
        (__attribute__((address_space(3))) void*)l, 16, 0, 0);
}

// ---------------- zero output + counts ----------------
__global__ void zero_out_kernel(float* __restrict__ out, int n, int* __restrict__ counts) {
    if (blockIdx.x == 0 && threadIdx.x < N_EXP) counts[threadIdx.x] = 0;
    int stride = gridDim.x * blockDim.x;
    float4 z = make_float4(0.f, 0.f, 0.f, 0.f);
    for (int i = blockIdx.x * blockDim.x + threadIdx.x; i < n / 4; i += stride)
        ((float4*)out)[i] = z;
}

// ---------------- fp32 -> bf16 convert (weights) ----------------
__global__ void cvt_bf16_kernel(const float* __restrict__ in, unsigned short* __restrict__ outp, int n) {
    int stride = gridDim.x * blockDim.x;
    for (int i = blockIdx.x * blockDim.x + threadIdx.x; i < n / 4; i += stride) {
        float4 v = ((const float4*)in)[i];
        ushort4 o;
        o.x = f2bf(v.x); o.y = f2bf(v.y); o.z = f2bf(v.z); o.w = f2bf(v.w);
        ((ushort4*)outp)[i] = o;
    }
}

// ---------------- router (fused: also emits x in bf16) ----------------
__global__ __launch_bounds__(64) void router_kernel(
        const float* __restrict__ x, const float* __restrict__ gw,
        int* __restrict__ counts, int* __restrict__ ltok, float* __restrict__ lw,
        unsigned short* __restrict__ xb) {
    int n = blockIdx.x;
    int lane = threadIdx.x;
    const float* xr = x + (size_t)n * D_MODEL;
    unsigned short* xbr = xb + (size_t)n * D_MODEL;
    float acc[N_EXP];
    #pragma unroll
    for (int e = 0; e < N_EXP; e++) acc[e] = 0.f;
    #pragma unroll
    for (int i = 0; i < 4; i++) {
        int j = lane + i * 64;                  // float4 index
        float4 v = ((const float4*)xr)[j];
        ushort4 o;
        o.x = f2bf(v.x); o.y = f2bf(v.y); o.z = f2bf(v.z); o.w = f2bf(v.w);
        ((ushort4*)xbr)[j] = o;
        int d = j * 4;
        #pragma unroll
        for (int e = 0; e < N_EXP; e++) {
            const float* g = gw + e * D_MODEL + d;
            acc[e] += v.x * g[0] + v.y * g[1] + v.z * g[2] + v.w * g[3];
        }
    }
    #pragma unroll
    for (int e = 0; e < N_EXP; e++) {
        #pragma unroll
        for (int off = 32; off > 0; off >>= 1)
            acc[e] += __shfl_down(acc[e], off);
    }
    if (lane == 0) {
        float mx = acc[0];
        #pragma unroll
        for (int e = 1; e < N_EXP; e++) mx = fmaxf(mx, acc[e]);
        float p[N_EXP];
        float s = 0.f;
        #pragma unroll
        for (int e = 0; e < N_EXP; e++) { p[e] = expf(acc[e] - mx); s += p[e]; }
        float inv = 1.f / s;
        #pragma unroll
        for (int e = 0; e < N_EXP; e++) p[e] *= inv;
        int i0 = 0;
        #pragma unroll
        for (int e = 1; e < N_EXP; e++) if (p[e] > p[i0]) i0 = e;
        int i1 = (i0 == 0) ? 1 : 0;
        #pragma unroll
        for (int e = 0; e < N_EXP; e++) if (e != i0 && p[e] > p[i1]) i1 = e;
        float s2 = p[i0] + p[i1] + 1e-9f;
        float w0 = p[i0] / s2, w1 = p[i1] / s2;
        int pos0 = atomicAdd(&counts[i0], 1);
        ltok[i0 * NTOK + pos0] = n; lw[i0 * NTOK + pos0] = w0;
        int pos1 = atomicAdd(&counts[i1], 1);
        ltok[i1 * NTOK + pos1] = n; lw[i1 * NTOK + pos1] = w1;
    }
}

// ---------------- exclusive scan over 8 expert counts ----------------
__global__ void scan_kernel(const int* __restrict__ counts, int* __restrict__ offs) {
    if (threadIdx.x == 0 && blockIdx.x == 0) {
        int s = 0;
        for (int e = 0; e < N_EXP; e++) { offs[e] = s; s += counts[e]; }
    }
}

// =====================================================================
// m97-regime grouped GEMM (r4, verified: conflicts=0, FETCH minimal).
// r5: gemm2 gets SPLITK=4 -> 4x active blocks (depth 4->16 per CU) to fix
// the 24%-occupancy parallelism starvation; atomic epilogue composes
// across splits, b2 added by split 0 only.
// =====================================================================

// GEMM1: h = relu(X_gathered @ W1[e]^T + b1[e])
__global__ __launch_bounds__(THREADS, 4) void gemm1_kernel(
        const unsigned short* __restrict__ xb, const unsigned short* __restrict__ w1b,
        const float* __restrict__ b1,
        const int* __restrict__ counts, const int* __restrict__ offs,
        const int* __restrict__ ltok,
        unsigned short* __restrict__ hb) {
    const int NTM = NTOK / BM;   // 64 (worst case)
    int b = blockIdx.x;
    int e = b & 7;               // expert -> XCD
    int idx = b >> 3;
    int nt = idx / NTM;          // W-panel major: co-resident blocks share nt
    int mt = idx % NTM;
    int cnt = counts[e];
    if (mt * BM >= cnt) return;

    __shared__ __align__(16) unsigned short As[BM * BK];   // 16 KB
    __shared__ __align__(16) unsigned short Bs[BN * BK];   // 16 KB

    int t = threadIdx.x;
    int lane = t & 63, w = t >> 6;     // 4 waves
    int wr = w >> 1, wc = w & 1;       // 2 x 2

    int srow = t >> 3;                       // 0..31
    int schunk = (t & 7) ^ (srow & 7);
    const unsigned short* aptr[4];
    const unsigned short* bptr[4];
    #pragma unroll
    for (int j = 0; j < 4; j++) {
        int rr = srow + j * 32;
        int slot = mt * BM + rr;
        int cs = slot < cnt ? slot : (cnt - 1);
        int tok = ltok[e * NTOK + cs];
        aptr[j] = xb + (size_t)tok * D_MODEL + schunk * 8;
        bptr[j] = w1b + ((size_t)e * D_FF + nt * BN + rr) * D_MODEL + schunk * 8;
    }
    char* As_b = (char*)As;
    char* Bs_b = (char*)Bs;

    int arow_base = wr * 64 + (lane & 15);
    int brow_base = wc * 64 + (lane & 15);
    int ch[2];
    #pragma unroll
    for (int ks = 0; ks < 2; ks++)
        ch[ks] = ((ks * 4 + (lane >> 4)) ^ (lane & 7)) << 4;

    f32x4 acc[4][4];
    #pragma unroll
    for (int m = 0; m < 4; m++)
        #pragma unroll
        for (int n = 0; n < 4; n++)
            acc[m][n] = (f32x4){0.f, 0.f, 0.f, 0.f};

    for (int k0 = 0; k0 < D_MODEL; k0 += BK) {
        #pragma unroll
        for (int j = 0; j < 4; j++) {
            gload_lds16(aptr[j] + k0, As_b + j * 4096 + t * 16);
            gload_lds16(bptr[j] + k0, Bs_b + j * 4096 + t * 16);
        }
        __syncthreads();
        bf16x8 af[2][4], bf[2][4];
        #pragma unroll
        for (int ks = 0; ks < 2; ks++) {
            #pragma unroll
            for (int m = 0; m < 4; m++)
                af[ks][m] = *(const bf16x8*)(As_b + (size_t)(arow_base + m * 16) * 128 + ch[ks]);
            #pragma unroll
            for (int n = 0; n < 4; n++)
                bf[ks][n] = *(const bf16x8*)(Bs_b + (size_t)(brow_base + n * 16) * 128 + ch[ks]);
        }
        #pragma unroll
        for (int ks = 0; ks < 2; ks++)
            #pragma unroll
            for (int m = 0; m < 4; m++)
                #pragma unroll
                for (int n = 0; n < 4; n++)
                    acc[m][n] = __builtin_amdgcn_mfma_f32_16x16x32_bf16(af[ks][m], bf[ks][n], acc[m][n], 0, 0, 0);
        __syncthreads();
    }

    int hbase = offs[e];
    float biasv[4];
    #pragma unroll
    for (int n = 0; n < 4; ++n)
        biasv[n] = b1[e * D_FF + nt * BN + wc * 64 + n * 16 + (lane & 15)];
    #pragma unroll
    for (int m = 0; m < 4; ++m) {
        int s0 = mt * BM + wr * 64 + m * 16 + (lane >> 4) * 4;
        #pragma unroll
        for (int rq = 0; rq < 4; ++rq) {
            int s = s0 + rq;
            if (s < cnt) {
                size_t rowoff = (size_t)(hbase + s) * D_FF + nt * BN + wc * 64 + (lane & 15);
                #pragma unroll
                for (int n = 0; n < 4; ++n) {
                    float v = fmaxf(acc[m][n][rq] + biasv[n], 0.f);
                    hb[rowoff + n * 16] = f2bf(v);
                }
            }
        }
    }
}

// GEMM2 (split-K): y += h @ W2[e]^T (+ b2 on split 0); weighted atomic scatter
__global__ __launch_bounds__(THREADS, 4) void gemm2_kernel(
        const unsigned short* __restrict__ hb, const unsigned short* __restrict__ w2b,
        const float* __restrict__ b2,
        const int* __restrict__ counts, const int* __restrict__ offs,
        const int* __restrict__ ltok, const float* __restrict__ lw,
        float* __restrict__ out) {
    const int NTM = NTOK / BM;     // 64
    const int NTN = D_MODEL / BN;  // 8
    const int KC = D_FF / SPLITK;  // 1024
    int b = blockIdx.x;
    int e = b & 7;
    int idx = b >> 3;
    int mt = idx % NTM;
    int rest = idx / NTM;
    int nt = rest % NTN;
    int sk = rest / NTN;
    int cnt = counts[e];
    if (mt * BM >= cnt) return;
    int hbase = offs[e];
    int kbase = sk * KC;

    __shared__ __align__(16) unsigned short As[BM * BK];
    __shared__ __align__(16) unsigned short Bs[BN * BK];

    int t = threadIdx.x;
    int lane = t & 63, w = t >> 6;
    int wr = w >> 1, wc = w & 1;

    int srow = t >> 3;
    int schunk = (t & 7) ^ (srow & 7);
    const unsigned short* aptr[4];
    const unsigned short* bptr[4];
    #pragma unroll
    for (int j = 0; j < 4; j++) {
        int rr = srow + j * 32;
        int slot = mt * BM + rr;
        int cs = slot < cnt ? slot : (cnt - 1);
        aptr[j] = hb + (size_t)(hbase + cs) * D_FF + kbase + schunk * 8;
        bptr[j] = w2b + ((size_t)e * D_MODEL + nt * BN + rr) * D_FF + kbase + schunk * 8;
    }
    char* As_b = (char*)As;
    char* Bs_b = (char*)Bs;

    int arow_base = wr * 64 + (lane & 15);
    int brow_base = wc * 64 + (lane & 15);
    int ch[2];
    #pragma unroll
    for (int ks = 0; ks < 2; ks++)
        ch[ks] = ((ks * 4 + (lane >> 4)) ^ (lane & 7)) << 4;

    f32x4 acc[4][4];
    #pragma unroll
    for (int m = 0; m < 4; m++)
        #pragma unroll
        for (int n = 0; n < 4; n++)
            acc[m][n] = (f32x4){0.f, 0.f, 0.f, 0.f};

    for (int k0 = 0; k0 < KC; k0 += BK) {
        #pragma unroll
        for (int j = 0; j < 4; j++) {
            gload_lds16(aptr[j] + k0, As_b + j * 4096 + t * 16);
            gload_lds16(bptr[j] + k0, Bs_b + j * 4096 + t * 16);
        }
        __syncthreads();
        bf16x8 af[2][4], bf[2][4];
        #pragma unroll
        for (int ks = 0; ks < 2; ks++) {
            #pragma unroll
            for (int m = 0; m < 4; m++)
                af[ks][m] = *(const bf16x8*)(As_b + (size_t)(arow_base + m * 16) * 128 + ch[ks]);
            #pragma unroll
            for (int n = 0; n < 4; n++)
                bf[ks][n] = *(const bf16x8*)(Bs_b + (size_t)(brow_base + n * 16) * 128 + ch[ks]);
        }
        #pragma unroll
        for (int ks = 0; ks < 2; ks++)
            #pragma unroll
            for (int m = 0; m < 4; m++)
                #pragma unroll
                for (int n = 0; n < 4; n++)
                    acc[m][n] = __builtin_amdgcn_mfma_f32_16x16x32_bf16(af[ks][m], bf[ks][n], acc[m][n], 0, 0, 0);
        __syncthreads();
    }

    // epilogue: weighted atomic scatter; b2 only on split 0
    int lbase = e * NTOK;
    float biasv[4];
    #pragma unroll
    for (int n = 0; n < 4; ++n)
        biasv[n] = (sk == 0) ? b2[e * D_MODEL + nt * BN + wc * 64 + n * 16 + (lane & 15)] : 0.f;
    #pragma unroll
    for (int m = 0; m < 4; ++m) {
        int s0 = mt * BM + wr * 64 + m * 16 + (lane >> 4) * 4;
        #pragma unroll
        for (int rq = 0; rq < 4; ++rq) {
            int s = s0 + rq;
            if (s >= cnt) continue;
            int tok = ltok[lbase + s];
            float wgt = lw[lbase + s];
            float* orow = out + (size_t)tok * D_MODEL + nt * BN + wc * 64 + (lane & 15);
            #pragma unroll
            for (int n = 0; n < 4; ++n)
                atomicAdd(orow + n * 16, wgt * (acc[m][n][rq] + biasv[n]));
        }
    }
}

extern "C" void kernel_launch(void* const* d_in, const int* in_sizes, int n_in,
                              void* d_out, int out_size, void* d_ws, size_t ws_size,
                              hipStream_t stream) {
    const float* x  = (const float*)d_in[0];
    const float* gw = (const float*)d_in[1];
    const float* W1 = (const float*)d_in[2];
    const float* b1 = (const float*)d_in[3];
    const float* W2 = (const float*)d_in[4];
    const float* b2 = (const float*)d_in[5];
    float* out = (float*)d_out;

    char* ws = (char*)d_ws;
    size_t off = 0;
    auto alloc = [&](size_t bytes) -> char* {
        char* p = ws + off;
        off += (bytes + 255) & ~(size_t)255;
        return p;
    };
    unsigned short* xb  = (unsigned short*)alloc((size_t)NTOK * D_MODEL * 2);
    unsigned short* w1b = (unsigned short*)alloc((size_t)N_EXP * D_FF * D_MODEL * 2);
    unsigned short* w2b = (unsigned short*)alloc((size_t)N_EXP * D_MODEL * D_FF * 2);
    unsigned short* hb  = (unsigned short*)alloc((size_t)NASSIGN * D_FF * 2);
    int*   counts = (int*)alloc(256);
    int*   offs   = (int*)alloc(256);
    int*   ltok   = (int*)alloc((size_t)N_EXP * NTOK * 4);
    float* lw     = (float*)alloc((size_t)N_EXP * NTOK * 4);

    zero_out_kernel<<<2048, 256, 0, stream>>>(out, out_size, counts);
    cvt_bf16_kernel<<<4096, 256, 0, stream>>>(W1, w1b, N_EXP * D_FF * D_MODEL);
    cvt_bf16_kernel<<<4096, 256, 0, stream>>>(W2, w2b, N_EXP * D_MODEL * D_FF);
    router_kernel<<<NTOK, 64, 0, stream>>>(x, gw, counts, ltok, lw, xb);
    scan_kernel<<<1, 64, 0, stream>>>(counts, offs);
    gemm1_kernel<<<N_EXP * (NTOK / BM) * (D_FF / BN), THREADS, 0, stream>>>(
        xb, w1b, b1, counts, offs, ltok, hb);
    gemm2_kernel<<<N_EXP * (NTOK / BM) * (D_MODEL / BN) * SPLITK, THREADS, 0, stream>>>(
        hb, w2b, b2, counts, offs, ltok, lw, out);
}

// Round 6
// 704.139 us; speedup vs baseline: 1.1584x; 1.1584x over previous
//
#include <hip/hip_runtime.h>
#include <hip/hip_bf16.h>
#include <stdint.h>

#define D_MODEL 1024
#define D_FF    4096
#define N_EXP   8
#define TOPK    2
#define NTOK    8192
#define NASSIGN (NTOK*TOPK)

#define BM 128
#define BN 128
#define BK 64
#define THREADS 256
#define SPLITK 2          // gemm2 K-split: 4096 -> 2 x 2048 (depth 8, atomics x2 only)

typedef __bf16 bf16_t;
typedef __attribute__((ext_vector_type(8))) bf16_t bf16x8;
typedef __attribute__((ext_vector_type(4))) float f32x4;

__device__ __forceinline__ unsigned short f2bf(float f) {
    bf16_t b = (bf16_t)f;
    return __builtin_bit_cast(unsigned short, b);
}

__device__ __forceinline__ void gload_lds16(const void* g, void* l) {
    __builtin_amdgcn_global_load_lds(
        (const __attribute__((address_space(1))) void*)g,
        (__attribute__((address_space(3))) void*)l, 16, 0, 0);
}

// ---------------- zero output + counts ----------------
__global__ void zero_out_kernel(float* __restrict__ out, int n, int* __restrict__ counts) {
    if (blockIdx.x == 0 && threadIdx.x < N_EXP) counts[threadIdx.x] = 0;
    int stride = gridDim.x * blockDim.x;
    float4 z = make_float4(0.f, 0.f, 0.f, 0.f);
    for (int i = blockIdx.x * blockDim.x + threadIdx.x; i < n / 4; i += stride)
        ((float4*)out)[i] = z;
}

// ---------------- router (fused: also emits x in bf16) ----------------
__global__ __launch_bounds__(64) void router_kernel(
        const float* __restrict__ x, const float* __restrict__ gw,
        int* __restrict__ counts, int* __restrict__ ltok, float* __restrict__ lw,
        unsigned short* __restrict__ xb) {
    int n = blockIdx.x;
    int lane = threadIdx.x;
    const float* xr = x + (size_t)n * D_MODEL;
    unsigned short* xbr = xb + (size_t)n * D_MODEL;
    float acc[N_EXP];
    #pragma unroll
    for (int e = 0; e < N_EXP; e++) acc[e] = 0.f;
    #pragma unroll
    for (int i = 0; i < 4; i++) {
        int j = lane + i * 64;                  // float4 index
        float4 v = ((const float4*)xr)[j];
        ushort4 o;
        o.x = f2bf(v.x); o.y = f2bf(v.y); o.z = f2bf(v.z); o.w = f2bf(v.w);
        ((ushort4*)xbr)[j] = o;
        int d = j * 4;
        #pragma unroll
        for (int e = 0; e < N_EXP; e++) {
            const float* g = gw + e * D_MODEL + d;
            acc[e] += v.x * g[0] + v.y * g[1] + v.z * g[2] + v.w * g[3];
        }
    }
    #pragma unroll
    for (int e = 0; e < N_EXP; e++) {
        #pragma unroll
        for (int off = 32; off > 0; off >>= 1)
            acc[e] += __shfl_down(acc[e], off);
    }
    if (lane == 0) {
        float mx = acc[0];
        #pragma unroll
        for (int e = 1; e < N_EXP; e++) mx = fmaxf(mx, acc[e]);
        float p[N_EXP];
        float s = 0.f;
        #pragma unroll
        for (int e = 0; e < N_EXP; e++) { p[e] = expf(acc[e] - mx); s += p[e]; }
        float inv = 1.f / s;
        #pragma unroll
        for (int e = 0; e < N_EXP; e++) p[e] *= inv;
        int i0 = 0;
        #pragma unroll
        for (int e = 1; e < N_EXP; e++) if (p[e] > p[i0]) i0 = e;
        int i1 = (i0 == 0) ? 1 : 0;
        #pragma unroll
        for (int e = 0; e < N_EXP; e++) if (e != i0 && p[e] > p[i1]) i1 = e;
        float s2 = p[i0] + p[i1] + 1e-9f;
        float w0 = p[i0] / s2, w1 = p[i1] / s2;
        int pos0 = atomicAdd(&counts[i0], 1);
        ltok[i0 * NTOK + pos0] = n; lw[i0 * NTOK + pos0] = w0;
        int pos1 = atomicAdd(&counts[i1], 1);
        ltok[i1 * NTOK + pos1] = n; lw[i1 * NTOK + pos1] = w1;
    }
}

// ---------------- exclusive scan over 8 expert counts ----------------
__global__ void scan_kernel(const int* __restrict__ counts, int* __restrict__ offs) {
    if (threadIdx.x == 0 && blockIdx.x == 0) {
        int s = 0;
        for (int e = 0; e < N_EXP; e++) { offs[e] = s; s += counts[e]; }
    }
}

// =====================================================================
// r6: W stays fp32 in HBM; conversion fused into GEMM B-staging
// (reg-stage: float4 loads -> cvt -> swizzled ds_write_b128). Kills the
// two cvt kernels (~130us of pure BW). A-side keeps gload_lds (verified
// conflict-free). gemm2: SPLITK=2 (depth 8, atomics only 2x r4).
// =====================================================================

// B-staging helper: load 4 rows of fp32 W (32B each) -> bf16 -> LDS swizzled.
// Thread t handles rows (t>>3)+j*32, fp32 chunk (t&7)*8 floats; writes LDS
// slot (t&7)^(row&7) so LDS[r][s] holds chunk s^(r&7) (matches read XOR).
__device__ __forceinline__ void stage_B_f32(
        const float* __restrict__ bsrcf[4], int k0, unsigned short* Bs, int t) {
    #pragma unroll
    for (int j = 0; j < 4; j++) {
        int rr = (t >> 3) + j * 32;
        const float4* p = (const float4*)(bsrcf[j] + k0);
        float4 v0 = p[0];
        float4 v1 = p[1];
        ushort4 o0, o1;
        o0.x = f2bf(v0.x); o0.y = f2bf(v0.y); o0.z = f2bf(v0.z); o0.w = f2bf(v0.w);
        o1.x = f2bf(v1.x); o1.y = f2bf(v1.y); o1.z = f2bf(v1.z); o1.w = f2bf(v1.w);
        int slot = (t & 7) ^ (rr & 7);
        ushort4* dst = (ushort4*)((char*)Bs + rr * 128 + slot * 16);
        dst[0] = o0;
        dst[1] = o1;
    }
}

// GEMM1: h = relu(X_gathered @ W1[e]^T + b1[e]),  W1 read as fp32
__global__ __launch_bounds__(THREADS, 4) void gemm1_kernel(
        const unsigned short* __restrict__ xb, const float* __restrict__ W1,
        const float* __restrict__ b1,
        const int* __restrict__ counts, const int* __restrict__ offs,
        const int* __restrict__ ltok,
        unsigned short* __restrict__ hb) {
    const int NTM = NTOK / BM;   // 64 (worst case)
    int b = blockIdx.x;
    int e = b & 7;               // expert -> XCD
    int idx = b >> 3;
    int nt = idx / NTM;          // W-panel major: co-resident blocks share nt
    int mt = idx % NTM;
    int cnt = counts[e];
    if (mt * BM >= cnt) return;

    __shared__ __align__(16) unsigned short As[BM * BK];   // 16 KB
    __shared__ __align__(16) unsigned short Bs[BN * BK];   // 16 KB

    int t = threadIdx.x;
    int lane = t & 63, w = t >> 6;     // 4 waves
    int wr = w >> 1, wc = w & 1;       // 2 x 2

    int srow = t >> 3;                       // 0..31
    int schunk = (t & 7) ^ (srow & 7);
    const unsigned short* aptr[4];
    const float* bptrf[4];
    #pragma unroll
    for (int j = 0; j < 4; j++) {
        int rr = srow + j * 32;
        int slot = mt * BM + rr;
        int cs = slot < cnt ? slot : (cnt - 1);
        int tok = ltok[e * NTOK + cs];
        aptr[j] = xb + (size_t)tok * D_MODEL + schunk * 8;
        bptrf[j] = W1 + ((size_t)e * D_FF + nt * BN + rr) * D_MODEL + (t & 7) * 8;
    }
    char* As_b = (char*)As;
    char* Bs_b = (char*)Bs;

    int arow_base = wr * 64 + (lane & 15);
    int brow_base = wc * 64 + (lane & 15);
    int ch[2];
    #pragma unroll
    for (int ks = 0; ks < 2; ks++)
        ch[ks] = ((ks * 4 + (lane >> 4)) ^ (lane & 7)) << 4;

    f32x4 acc[4][4];
    #pragma unroll
    for (int m = 0; m < 4; m++)
        #pragma unroll
        for (int n = 0; n < 4; n++)
            acc[m][n] = (f32x4){0.f, 0.f, 0.f, 0.f};

    for (int k0 = 0; k0 < D_MODEL; k0 += BK) {
        #pragma unroll
        for (int j = 0; j < 4; j++)
            gload_lds16(aptr[j] + k0, As_b + j * 4096 + t * 16);
        stage_B_f32(bptrf, k0, Bs, t);
        __syncthreads();
        bf16x8 af[2][4], bf[2][4];
        #pragma unroll
        for (int ks = 0; ks < 2; ks++) {
            #pragma unroll
            for (int m = 0; m < 4; m++)
                af[ks][m] = *(const bf16x8*)(As_b + (size_t)(arow_base + m * 16) * 128 + ch[ks]);
            #pragma unroll
            for (int n = 0; n < 4; n++)
                bf[ks][n] = *(const bf16x8*)(Bs_b + (size_t)(brow_base + n * 16) * 128 + ch[ks]);
        }
        #pragma unroll
        for (int ks = 0; ks < 2; ks++)
            #pragma unroll
            for (int m = 0; m < 4; m++)
                #pragma unroll
                for (int n = 0; n < 4; n++)
                    acc[m][n] = __builtin_amdgcn_mfma_f32_16x16x32_bf16(af[ks][m], bf[ks][n], acc[m][n], 0, 0, 0);
        __syncthreads();
    }

    int hbase = offs[e];
    float biasv[4];
    #pragma unroll
    for (int n = 0; n < 4; ++n)
        biasv[n] = b1[e * D_FF + nt * BN + wc * 64 + n * 16 + (lane & 15)];
    #pragma unroll
    for (int m = 0; m < 4; ++m) {
        int s0 = mt * BM + wr * 64 + m * 16 + (lane >> 4) * 4;
        #pragma unroll
        for (int rq = 0; rq < 4; ++rq) {
            int s = s0 + rq;
            if (s < cnt) {
                size_t rowoff = (size_t)(hbase + s) * D_FF + nt * BN + wc * 64 + (lane & 15);
                #pragma unroll
                for (int n = 0; n < 4; ++n) {
                    float v = fmaxf(acc[m][n][rq] + biasv[n], 0.f);
                    hb[rowoff + n * 16] = f2bf(v);
                }
            }
        }
    }
}

// GEMM2 (split-K=2): y += h @ W2[e]^T (+ b2 on split 0); W2 read fp32;
// weighted atomic scatter.
__global__ __launch_bounds__(THREADS, 4) void gemm2_kernel(
        const unsigned short* __restrict__ hb, const float* __restrict__ W2,
        const float* __restrict__ b2,
        const int* __restrict__ counts, const int* __restrict__ offs,
        const int* __restrict__ ltok, const float* __restrict__ lw,
        float* __restrict__ out) {
    const int NTM = NTOK / BM;     // 64
    const int NTN = D_MODEL / BN;  // 8
    const int KC = D_FF / SPLITK;  // 2048
    int b = blockIdx.x;
    int e = b & 7;
    int idx = b >> 3;
    int mt = idx % NTM;
    int rest = idx / NTM;
    int nt = rest % NTN;
    int sk = rest / NTN;
    int cnt = counts[e];
    if (mt * BM >= cnt) return;
    int hbase = offs[e];
    int kbase = sk * KC;

    __shared__ __align__(16) unsigned short As[BM * BK];
    __shared__ __align__(16) unsigned short Bs[BN * BK];

    int t = threadIdx.x;
    int lane = t & 63, w = t >> 6;
    int wr = w >> 1, wc = w & 1;

    int srow = t >> 3;
    int schunk = (t & 7) ^ (srow & 7);
    const unsigned short* aptr[4];
    const float* bptrf[4];
    #pragma unroll
    for (int j = 0; j < 4; j++) {
        int rr = srow + j * 32;
        int slot = mt * BM + rr;
        int cs = slot < cnt ? slot : (cnt - 1);
        aptr[j] = hb + (size_t)(hbase + cs) * D_FF + kbase + schunk * 8;
        bptrf[j] = W2 + ((size_t)e * D_MODEL + nt * BN + rr) * D_FF + kbase + (t & 7) * 8;
    }
    char* As_b = (char*)As;
    char* Bs_b = (char*)Bs;

    int arow_base = wr * 64 + (lane & 15);
    int brow_base = wc * 64 + (lane & 15);
    int ch[2];
    #pragma unroll
    for (int ks = 0; ks < 2; ks++)
        ch[ks] = ((ks * 4 + (lane >> 4)) ^ (lane & 7)) << 4;

    f32x4 acc[4][4];
    #pragma unroll
    for (int m = 0; m < 4; m++)
        #pragma unroll
        for (int n = 0; n < 4; n++)
            acc[m][n] = (f32x4){0.f, 0.f, 0.f, 0.f};

    for (int k0 = 0; k0 < KC; k0 += BK) {
        #pragma unroll
        for (int j = 0; j < 4; j++)
            gload_lds16(aptr[j] + k0, As_b + j * 4096 + t * 16);
        stage_B_f32(bptrf, k0, Bs, t);
        __syncthreads();
        bf16x8 af[2][4], bf[2][4];
        #pragma unroll
        for (int ks = 0; ks < 2; ks++) {
            #pragma unroll
            for (int m = 0; m < 4; m++)
                af[ks][m] = *(const bf16x8*)(As_b + (size_t)(arow_base + m * 16) * 128 + ch[ks]);
            #pragma unroll
            for (int n = 0; n < 4; n++)
                bf[ks][n] = *(const bf16x8*)(Bs_b + (size_t)(brow_base + n * 16) * 128 + ch[ks]);
        }
        #pragma unroll
        for (int ks = 0; ks < 2; ks++)
            #pragma unroll
            for (int m = 0; m < 4; m++)
                #pragma unroll
                for (int n = 0; n < 4; n++)
                    acc[m][n] = __builtin_amdgcn_mfma_f32_16x16x32_bf16(af[ks][m], bf[ks][n], acc[m][n], 0, 0, 0);
        __syncthreads();
    }

    // epilogue: weighted atomic scatter; b2 only on split 0
    int lbase = e * NTOK;
    float biasv[4];
    #pragma unroll
    for (int n = 0; n < 4; ++n)
        biasv[n] = (sk == 0) ? b2[e * D_MODEL + nt * BN + wc * 64 + n * 16 + (lane & 15)] : 0.f;
    #pragma unroll
    for (int m = 0; m < 4; ++m) {
        int s0 = mt * BM + wr * 64 + m * 16 + (lane >> 4) * 4;
        #pragma unroll
        for (int rq = 0; rq < 4; ++rq) {
            int s = s0 + rq;
            if (s >= cnt) continue;
            int tok = ltok[lbase + s];
            float wgt = lw[lbase + s];
            float* orow = out + (size_t)tok * D_MODEL + nt * BN + wc * 64 + (lane & 15);
            #pragma unroll
            for (int n = 0; n < 4; ++n)
                atomicAdd(orow + n * 16, wgt * (acc[m][n][rq] + biasv[n]));
        }
    }
}

extern "C" void kernel_launch(void* const* d_in, const int* in_sizes, int n_in,
                              void* d_out, int out_size, void* d_ws, size_t ws_size,
                              hipStream_t stream) {
    const float* x  = (const float*)d_in[0];
    const float* gw = (const float*)d_in[1];
    const float* W1 = (const float*)d_in[2];
    const float* b1 = (const float*)d_in[3];
    const float* W2 = (const float*)d_in[4];
    const float* b2 = (const float*)d_in[5];
    float* out = (float*)d_out;

    char* ws = (char*)d_ws;
    size_t off = 0;
    auto alloc = [&](size_t bytes) -> char* {
        char* p = ws + off;
        off += (bytes + 255) & ~(size_t)255;
        return p;
    };
    unsigned short* xb  = (unsigned short*)alloc((size_t)NTOK * D_MODEL * 2);
    unsigned short* hb  = (unsigned short*)alloc((size_t)NASSIGN * D_FF * 2);
    int*   counts = (int*)alloc(256);
    int*   offs   = (int*)alloc(256);
    int*   ltok   = (int*)alloc((size_t)N_EXP * NTOK * 4);
    float* lw     = (float*)alloc((size_t)N_EXP * NTOK * 4);

    zero_out_kernel<<<2048, 256, 0, stream>>>(out, out_size, counts);
    router_kernel<<<NTOK, 64, 0, stream>>>(x, gw, counts, ltok, lw, xb);
    scan_kernel<<<1, 64, 0, stream>>>(counts, offs);
    gemm1_kernel<<<N_EXP * (NTOK / BM) * (D_FF / BN), THREADS, 0, stream>>>(
        xb, W1, b1, counts, offs, ltok, hb);
    gemm2_kernel<<<N_EXP * (NTOK / BM) * (D_MODEL / BN) * SPLITK, THREADS, 0, stream>>>(
        hb, W2, b2, counts, offs, ltok, lw, out);
}